// Round 1
// baseline (738.322 us; speedup 1.0000x reference)
//
#include <hip/hip_runtime.h>
#include <hip/hip_bf16.h>

// Problem constants (match the JAX reference)
#define NPT 65536
#define PATCH 14                      // P
#define CELLS (PATCH * PATCH * PATCH) // 2744
#define VEC4S (CELLS / 4)             // 686 float4 per depo (2744*4B = 10976B, 16B-aligned)
#define NSIGMA 3.0f
#define INV_SPACING 2.0f              // 1/0.5
#define SPACING_F 0.5f
#define SQRT2 1.41421356237309504880f

// One block per depo. 256 threads.
//  Phase 1: 45 threads compute cdf[a][e] = 0.5*erf(z) for a in 0..2, e in 0..14.
//  Phase 2: 42 threads diff into q[a][c], axis 0 premultiplied by charge.
//  Phase 3: all threads write the 14x14x14 outer product as 686 float4 stores.
__global__ __launch_bounds__(256) void raster_kernel(
    const float* __restrict__ sigma,   // (NPT,3)
    const float* __restrict__ time,    // (NPT,)
    const float* __restrict__ charge,  // (NPT,)
    const float* __restrict__ tail,    // (NPT,3)
    float* __restrict__ out_rast,      // (NPT, 14,14,14) fp32
    float* __restrict__ out_off)       // (NPT, 3) int offsets stored as fp32 values
{
    const int n = blockIdx.x;
    const int t = threadIdx.x;

    __shared__ float cdf[3][16];  // 15 edges per axis, padded
    __shared__ float q[3][16];    // 14 cells per axis, padded

    if (t < 45) {
        const int a = t / 15;       // axis
        const int e = t - a * 15;   // edge index 0..14
        const float sig = sigma[n * 3 + a];
        // center per reference _transform: axes permuted [tail1, tail0, time]
        float c;
        if (a == 0)      c = tail[n * 3 + 1];
        else if (a == 1) c = tail[n * 3 + 0];
        else             c = time[n];
        const float im = floorf((c - NSIGMA * sig) * INV_SPACING);  // exact vs /0.5
        const float edge = (im + (float)e) * SPACING_F;
        const float z = (edge - c) / (SQRT2 * sig);
        cdf[a][e] = 0.5f * erff(z);
        if (e == 0) {
            // int32 offset, stored as float (harness reads concatenated output as f32)
            out_off[n * 3 + a] = im;
        }
    }
    __syncthreads();

    if (t < 42) {
        const int a = t / 14;
        const int c = t - a * 14;
        float qq = cdf[a][c + 1] - cdf[a][c];
        if (a == 0) qq *= charge[n];
        q[a][c] = qq;
    }
    __syncthreads();

    // Coalesced float4 writes of the separable outer product.
    float4* __restrict__ out4 = (float4*)(out_rast + (size_t)n * CELLS);
    for (int c4 = t; c4 < VEC4S; c4 += 256) {
        const int base = c4 * 4;
        float4 v;
        float* vp = &v.x;
#pragma unroll
        for (int u = 0; u < 4; ++u) {
            const int cell = base + u;
            const int i = cell / (PATCH * PATCH);
            const int r = cell - i * (PATCH * PATCH);
            const int j = r / PATCH;
            const int k = r - j * PATCH;
            vp[u] = q[0][i] * q[1][j] * q[2][k];
        }
        out4[c4] = v;
    }
}

extern "C" void kernel_launch(void* const* d_in, const int* in_sizes, int n_in,
                              void* d_out, int out_size, void* d_ws, size_t ws_size,
                              hipStream_t stream) {
    const float* sigma  = (const float*)d_in[0];
    const float* time_  = (const float*)d_in[1];
    const float* charge = (const float*)d_in[2];
    const float* tail   = (const float*)d_in[3];

    float* out_rast = (float*)d_out;
    float* out_off  = (float*)d_out + (size_t)NPT * CELLS;  // offsets follow rasters

    raster_kernel<<<NPT, 256, 0, stream>>>(sigma, time_, charge, tail, out_rast, out_off);
}

// Round 4
// 730.843 us; speedup vs baseline: 1.0102x; 1.0102x over previous
//
#include <hip/hip_runtime.h>
#include <hip/hip_bf16.h>

// Problem constants (match the JAX reference)
#define NPT 65536
#define PATCH 14                      // P
#define CELLS (PATCH * PATCH * PATCH) // 2744
#define VEC4S (CELLS / 4)             // 686 float4 per depo (10976B, 16B-aligned)

typedef float f4 __attribute__((ext_vector_type(4)));  // native vec for nontemporal builtin

// One depo per WAVE (4 depos per 256-thread block).
//  Phase 1: all 64 lanes compute cdf edges (lanes 0..44 meaningful, rest clamped),
//           1D profiles via __shfl_down diff -> LDS (per-wave region).
//  Phase 2: each wave streams its depo's 2744 cells as 686 float4 NT stores.
__global__ __launch_bounds__(256) void raster_kernel(
    const float* __restrict__ sigma,   // (NPT,3)
    const float* __restrict__ time_,   // (NPT,)
    const float* __restrict__ charge,  // (NPT,)
    const float* __restrict__ tail,    // (NPT,3)
    float* __restrict__ out_rast,      // (NPT,14,14,14) fp32
    float* __restrict__ out_off)       // (NPT,3) int offsets as fp32 values
{
    const int lane = threadIdx.x & 63;
    const int wv   = threadIdx.x >> 6;
    const int n    = (blockIdx.x << 2) | wv;

    __shared__ float q_s[4][3][16];    // per-wave 1D profiles (axis-0 pre-scaled by charge)

    // ---- Phase 1: CDF edges + diff, fully wave-parallel ----
    {
        int a = lane / 15;             // 0..4 (lanes >=45 do clamped redundant work)
        int e = lane - a * 15;         // 0..14
        int ac = (a < 3) ? a : 2;
        float sig = sigma[n * 3 + ac];
        // reference _transform: centers = [tail1, tail0, time]
        float c = (ac == 0) ? tail[n * 3 + 1]
                : (ac == 1) ? tail[n * 3 + 0]
                            : time_[n];
        float im   = floorf((c - 3.0f * sig) * 2.0f);     // /0.5 == *2 exactly
        float edge = (im + (float)e) * 0.5f;
        float z    = (edge - c) / (1.41421356237f * sig);
        float cdf  = 0.5f * erff(z);
        float cdfn = __shfl_down(cdf, 1);                  // cdf at edge e+1
        if (a < 3) {
            if (e == 0) out_off[n * 3 + a] = im;           // int offset as f32 value
            if (e < 14) {
                float qq = cdfn - cdf;
                if (a == 0) qq *= charge[n];
                q_s[wv][a][e] = qq;
            }
        }
    }
    __syncthreads();

    // ---- Phase 2: separable outer product, 686 float4 per wave ----
    const float* qw = &q_s[wv][0][0];
    f4* __restrict__ out4 = (f4*)(out_rast + (size_t)n * CELLS);
    for (int c4 = lane; c4 < VEC4S; c4 += 64) {
        const int base = c4 * 4;
        f4 v;
#pragma unroll
        for (int u = 0; u < 4; ++u) {
            const int cell = base + u;
            const int i = cell / (PATCH * PATCH);          // magic-mul div
            const int r = cell - i * (PATCH * PATCH);
            const int j = r / PATCH;
            const int k = r - j * PATCH;
            v[u] = qw[i] * qw[16 + j] * qw[32 + k];
        }
        __builtin_nontemporal_store(v, &out4[c4]);         // streaming output, skip cache
    }
}

extern "C" void kernel_launch(void* const* d_in, const int* in_sizes, int n_in,
                              void* d_out, int out_size, void* d_ws, size_t ws_size,
                              hipStream_t stream) {
    const float* sigma  = (const float*)d_in[0];
    const float* time_  = (const float*)d_in[1];
    const float* charge = (const float*)d_in[2];
    const float* tail   = (const float*)d_in[3];

    float* out_rast = (float*)d_out;
    float* out_off  = (float*)d_out + (size_t)NPT * CELLS;  // offsets follow rasters

    raster_kernel<<<NPT / 4, 256, 0, stream>>>(sigma, time_, charge, tail, out_rast, out_off);
}